// Round 7
// baseline (174.435 us; speedup 1.0000x reference)
//
#include <hip/hip_runtime.h>
#include <stdint.h>

#define TDIM 4096   // tokens = 2*2048
#define KDIM 4096   // IN_F
#define NDIM 4096   // OUT_F
#define RANK 128
#define NG   32
#define NCHUNK 64   // per-64-col partial-max chunks

typedef __attribute__((ext_vector_type(4))) int   i32x4;
typedef __attribute__((ext_vector_type(4))) float f32x4;
typedef __attribute__((ext_vector_type(8))) short short8;
typedef __attribute__((ext_vector_type(8))) unsigned short u16x8;

__device__ inline unsigned short f2bf(float f) {   // f32 -> bf16 RNE
    union { float f; unsigned u; } v; v.f = f;
    const unsigned r = v.u + 0x7FFF + ((v.u >> 16) & 1);
    return (unsigned short)(r >> 16);
}

// ---------------------------------------------------------------------------
// Kernel 1: per-token activation quantization (unchanged).
// ---------------------------------------------------------------------------
__global__ __launch_bounds__(256) void quant_x_kernel(
    const float* __restrict__ x, int8_t* __restrict__ xq,
    float* __restrict__ scale_x)
{
    const int row = blockIdx.x;
    const float4* xr = (const float4*)(x + (size_t)row * KDIM);
    __shared__ float4 buf[1024];
    __shared__ float wred[4];

    float m = 0.f;
    #pragma unroll
    for (int j = 0; j < 4; ++j) {
        const float4 v = xr[threadIdx.x + j * 256];
        buf[threadIdx.x + j * 256] = v;
        m = fmaxf(m, fmaxf(fmaxf(fabsf(v.x), fabsf(v.y)),
                           fmaxf(fabsf(v.z), fabsf(v.w))));
    }
    #pragma unroll
    for (int off = 32; off > 0; off >>= 1)
        m = fmaxf(m, __shfl_xor(m, off, 64));
    if ((threadIdx.x & 63) == 0) wred[threadIdx.x >> 6] = m;
    __syncthreads();
    const float mt = fmaxf(fmaxf(wred[0], wred[1]), fmaxf(wred[2], wred[3]));
    const float sx = mt / 127.0f;
    if (threadIdx.x == 0) scale_x[row] = sx;

    char4* xo = (char4*)(xq + (size_t)row * KDIM);
    #pragma unroll
    for (int j = 0; j < 4; ++j) {
        const float4 v = buf[threadIdx.x + j * 256];
        char4 q;
        q.x = (char)fminf(fmaxf(rintf(v.x / sx), -128.f), 127.f);
        q.y = (char)fminf(fmaxf(rintf(v.y / sx), -128.f), 127.f);
        q.z = (char)fminf(fmaxf(rintf(v.z / sx), -128.f), 127.f);
        q.w = (char)fminf(fmaxf(rintf(v.w / sx), -128.f), 127.f);
        xo[threadIdx.x + j * 256] = q;
    }
}

// ---------------------------------------------------------------------------
// Kernel 1b: convert svd factors to bf16 (unchanged).
// ---------------------------------------------------------------------------
__global__ __launch_bounds__(256) void conv_svd_kernel(
    const float* __restrict__ svd_up, const float* __restrict__ svd_down,
    unsigned short* __restrict__ upb, unsigned short* __restrict__ dnt)
{
    const int b = blockIdx.x;
    if (b < 256) {
        const int t = b * 256 + threadIdx.x;
        const int i  = t >> 4;
        const int k0 = (t & 15) * 8;
        u16x8 v;
        #pragma unroll
        for (int j = 0; j < 8; ++j)
            v[j] = f2bf(svd_down[(size_t)(k0 + j) * KDIM + i]);
        *(u16x8*)(dnt + (size_t)i * RANK + k0) = v;
    } else {
        const int t = (b - 256) * 256 + threadIdx.x;
        const float4* src = (const float4*)svd_up + (size_t)t * 4;
        #pragma unroll
        for (int h = 0; h < 2; ++h) {
            const float4 a = src[h * 2], c = src[h * 2 + 1];
            u16x8 v;
            v[0] = f2bf(a.x); v[1] = f2bf(a.y); v[2] = f2bf(a.z); v[3] = f2bf(a.w);
            v[4] = f2bf(c.x); v[5] = f2bf(c.y); v[6] = f2bf(c.z); v[7] = f2bf(c.w);
            *(u16x8*)(upb + (size_t)t * 16 + h * 8) = v;
        }
    }
}

// ---------------------------------------------------------------------------
// Kernel 2: W dequant via bf16 MFMA correction (unchanged).
// ---------------------------------------------------------------------------
__global__ __launch_bounds__(256) void w_pass1_mfma_kernel(
    const int* __restrict__ Wq, const float* __restrict__ scale,
    const float* __restrict__ zp,
    const unsigned short* __restrict__ upb,
    const unsigned short* __restrict__ dnt,
    float* __restrict__ Wf, float* __restrict__ partial_max)
{
    const int lane = threadIdx.x & 63, wid = threadIdx.x >> 6;
    const int wm = wid >> 1, wn = wid & 1;
    const int l15 = lane & 15, l16 = lane >> 4;
    const int row0 = blockIdx.x * 64 + wm * 32;
    const int col0 = blockIdx.y * 128 + wn * 64;

    short8 af[2][4], bfr[4][4];
    #pragma unroll
    for (int mi = 0; mi < 2; ++mi)
        #pragma unroll
        for (int kk = 0; kk < 4; ++kk)
            af[mi][kk] = *(const short8*)(upb +
                (size_t)(row0 + mi * 16 + l15) * RANK + kk * 32 + l16 * 8);
    #pragma unroll
    for (int ni = 0; ni < 4; ++ni)
        #pragma unroll
        for (int kk = 0; kk < 4; ++kk)
            bfr[ni][kk] = *(const short8*)(dnt +
                (size_t)(col0 + ni * 16 + l15) * RANK + kk * 32 + l16 * 8);

    f32x4 acc[2][4];
    #pragma unroll
    for (int mi = 0; mi < 2; ++mi)
        #pragma unroll
        for (int ni = 0; ni < 4; ++ni) acc[mi][ni] = (f32x4){0.f, 0.f, 0.f, 0.f};

    #pragma unroll
    for (int kk = 0; kk < 4; ++kk)
        #pragma unroll
        for (int mi = 0; mi < 2; ++mi)
            #pragma unroll
            for (int ni = 0; ni < 4; ++ni)
                acc[mi][ni] = __builtin_amdgcn_mfma_f32_16x16x32_bf16(
                    af[mi][kk], bfr[ni][kk], acc[mi][ni], 0, 0, 0);

    float rmax[2][4];
    #pragma unroll
    for (int mi = 0; mi < 2; ++mi)
        #pragma unroll
        for (int j = 0; j < 4; ++j) rmax[mi][j] = 0.f;

    #pragma unroll
    for (int ni = 0; ni < 4; ++ni) {
        const int col = col0 + ni * 16 + l15;
        const int g = col >> 7;
        #pragma unroll
        for (int mi = 0; mi < 2; ++mi) {
            #pragma unroll
            for (int j = 0; j < 4; ++j) {
                const int row = row0 + mi * 16 + l16 * 4 + j;
                const float s = scale[row * NG + g];
                const float z = zp[row * NG + g];
                const float q = (float)Wq[(size_t)row * KDIM + col];
                const float wf = (q - z) * s + acc[mi][ni][j];
                Wf[(size_t)row * KDIM + col] = wf;
                rmax[mi][j] = fmaxf(rmax[mi][j], fabsf(wf));
            }
        }
    }

    #pragma unroll
    for (int mi = 0; mi < 2; ++mi) {
        #pragma unroll
        for (int j = 0; j < 4; ++j) {
            float v = rmax[mi][j];
            v = fmaxf(v, __shfl_xor(v, 1, 64));
            v = fmaxf(v, __shfl_xor(v, 2, 64));
            v = fmaxf(v, __shfl_xor(v, 4, 64));
            v = fmaxf(v, __shfl_xor(v, 8, 64));
            if (l15 == 0) {
                const int row = row0 + mi * 16 + l16 * 4 + j;
                partial_max[(size_t)row * NCHUNK + blockIdx.y * 2 + wn] = v;
            }
        }
    }
}

__global__ __launch_bounds__(256) void finalize_sw_kernel(
    const float* __restrict__ partial_max, float* __restrict__ scale_w)
{
    const int o = blockIdx.x * 256 + threadIdx.x;
    const float4* p = (const float4*)(partial_max + (size_t)o * NCHUNK);
    float m = 0.f;
    #pragma unroll
    for (int i = 0; i < NCHUNK / 4; ++i) {
        const float4 v = p[i];
        m = fmaxf(m, fmaxf(fmaxf(v.x, v.y), fmaxf(v.z, v.w)));
    }
    scale_w[o] = m / 127.0f;
}

__global__ __launch_bounds__(256) void w_quant_kernel(
    const float* __restrict__ Wf, const float* __restrict__ scale_w,
    int8_t* __restrict__ wq)
{
    const size_t idx = ((size_t)blockIdx.x * 256 + threadIdx.x) * 4;
    const int o = (int)(idx >> 12);
    const float sw = scale_w[o];
    const float4 wf = *(const float4*)(Wf + idx);
    char4 q;
    q.x = (char)fminf(fmaxf(rintf(wf.x / sw), -128.f), 127.f);
    q.y = (char)fminf(fmaxf(rintf(wf.y / sw), -128.f), 127.f);
    q.z = (char)fminf(fmaxf(rintf(wf.z / sw), -128.f), 127.f);
    q.w = (char)fminf(fmaxf(rintf(wf.w / sw), -128.f), 127.f);
    *(char4*)(wq + idx) = q;
}

// ---------------------------------------------------------------------------
// Kernel 4: int8 GEMM — 128x256 tile, grid 512 = 2 BLOCKS/CU (R6 change).
// Rationale: R5's 256² grid=256 put exactly 1 block/CU — all 8 waves share
// one barrier clock, so ds_read and MFMA windows never overlap across waves,
// and the 64MB C-write epilogue ran chip-synchronized (~10 us serial tail).
// Two co-resident blocks drift independently (m114 overlap) and stagger
// epilogues. 8 waves (2Mx4N, per-wave 64x64, acc=64 regs, VGPR<=128 via
// __launch_bounds__(512,4) -> 4 waves/SIMD). LDS: 3-deep rotation,
// A 3x8KB + B 3x16KB = 72 KB -> 2 blocks = 144 <= 160 KB.
// Per K-tile: ONE phase {8 ds_read_b128 + 3 gload; BAR; 16 MFMA; vmcnt(3);
// BAR} — half the barriers of R5. Tile t stages t+2; vmcnt(3) after MFMA
// leaves t+2's 3 loads in flight, completes t+1; the following barrier
// publishes all waves' loads (per-wave vmcnt + barrier = block-wide safety,
// R5-validated pattern). Tail dummy stages (u clamped 63) target the
// rotation buffer consumed at t-1; counts stay uniform. vmcnt(0) after the
// loop before LDS teardown. Swizzle identical to R5 (measured conflicts=0):
// read slot l16^((lane>>1)&3), global source col pre-swizzled by
// sigma(srow)=(tid>>3)&3, LDS dest linear.
// ---------------------------------------------------------------------------
__global__ __launch_bounds__(512, 4) void gemm_i8_kernel(
    const int8_t* __restrict__ Aq,   // [T][K]
    const int8_t* __restrict__ Bq,   // [N][K]
    const float* __restrict__ scale_x, const float* __restrict__ scale_w,
    const float* __restrict__ bias, float* __restrict__ out)
{
    __shared__ __align__(16) int8_t lds[73728];
    // A: buf*8192 (128 rows x 64B), bufs 0..2 in [0, 24576)
    // B: 24576 + buf*16384 (256 rows x 64B)   in [24576, 73728)

    const int tid  = threadIdx.x;
    const int lane = tid & 63;
    const int wid  = tid >> 6;          // 0..7
    const int wmp  = wid >> 2;          // 0..1 (M)
    const int wnp  = wid & 3;           // 0..3 (N)
    const int l15  = lane & 15, l16 = lane >> 4;

    // XCD swizzle: 512 blocks, 64 consecutive per XCD (4 M-tiles x 16 N-tiles
    // share A/B panels in that XCD's L2).
    const int swz  = (blockIdx.x & 7) * 64 + (blockIdx.x >> 3);
    const int row0 = (swz >> 4) * 128;   // 32 M-tiles
    const int col0 = (swz & 15) * 256;   // 16 N-tiles

    // staging: 512 thr x 16B = 8KB per gload call; A = 1 call, B = 2 calls.
    const int srow = tid >> 2;           // 0..127
    const int scol = ((lane & 3) ^ ((lane >> 3) & 3)) * 16;  // inverse swizzle
    const int8_t* const A0 = Aq + (size_t)(row0 + srow) * KDIM + scol;
    const int8_t* const B0 = Bq + (size_t)(col0 + srow) * KDIM + scol;
    int8_t* const ldsw = lds + wid * 1024;   // wave-uniform dest base

#define STAGE_A(db, kt) \
    __builtin_amdgcn_global_load_lds( \
        (const __attribute__((address_space(1))) void*)(A0 + (kt) * 64), \
        (__attribute__((address_space(3))) void*)(ldsw + (db) * 8192), 16, 0, 0)
#define STAGE_B(db, h, kt) \
    __builtin_amdgcn_global_load_lds( \
        (const __attribute__((address_space(1))) void*)(B0 + (size_t)(h) * 128 * KDIM + (kt) * 64), \
        (__attribute__((address_space(3))) void*)(ldsw + 24576 + (db) * 16384 + (h) * 8192), 16, 0, 0)

    const int rslot = (l16 ^ ((lane >> 1) & 3)) * 16;
    const int aoff = (wmp * 64 + l15) * 64 + rslot;
    const int boff = (wnp * 64 + l15) * 64 + rslot;

    i32x4 Ar[4], Br[4];
    i32x4 acc[4][4];
    #pragma unroll
    for (int m = 0; m < 4; ++m)
        #pragma unroll
        for (int n = 0; n < 4; ++n) acc[m][n] = (i32x4){0, 0, 0, 0};

#define LDA(db) { const int8_t* p = lds + (db) * 8192 + aoff; \
    Ar[0] = *(const i32x4*)(p);        Ar[1] = *(const i32x4*)(p + 1024); \
    Ar[2] = *(const i32x4*)(p + 2048); Ar[3] = *(const i32x4*)(p + 3072); }
#define LDB(db) { const int8_t* p = lds + 24576 + (db) * 16384 + boff; \
    Br[0] = *(const i32x4*)(p);        Br[1] = *(const i32x4*)(p + 1024); \
    Br[2] = *(const i32x4*)(p + 2048); Br[3] = *(const i32x4*)(p + 3072); }
#define MMA_ALL { \
    _Pragma("unroll") for (int fm = 0; fm < 4; ++fm) \
    _Pragma("unroll") for (int fn = 0; fn < 4; ++fn) \
        acc[fm][fn] = __builtin_amdgcn_mfma_i32_16x16x64_i8( \
            Ar[fm], Br[fn], acc[fm][fn], 0, 0, 0); }

#define FENCE asm volatile("" ::: "memory")
#define BAR   __builtin_amdgcn_s_barrier()
#define VMCNT3 asm volatile("s_waitcnt vmcnt(3)" ::: "memory")
#define VMCNT0 asm volatile("s_waitcnt vmcnt(0)" ::: "memory")
#define PRIO1 __builtin_amdgcn_s_setprio(1)
#define PRIO0 __builtin_amdgcn_s_setprio(0)

    // Tile t: read buf rb=t%3, stage tile u=t+2 into sb=(t+2)%3.
#define TILE(rb, sb, u) { \
    LDA(rb); LDB(rb); \
    FENCE; STAGE_A(sb, u); STAGE_B(sb, 0, u); STAGE_B(sb, 1, u); \
    BAR; PRIO1; MMA_ALL; PRIO0; \
    VMCNT3; BAR; }

    // prologue: tiles 0,1 staged; vmcnt(3) -> tile 0 complete; barrier publishes.
    STAGE_A(0, 0); STAGE_B(0, 0, 0); STAGE_B(0, 1, 0);
    STAGE_A(1, 1); STAGE_B(1, 0, 1); STAGE_B(1, 1, 1);
    VMCNT3;
    BAR;

    for (int j = 0; j < 21; ++j) {        // tiles 0..62
        const int t0 = 3 * j;
        const int u1 = (t0 + 3 > 63) ? 63 : t0 + 3;
        const int u2 = (t0 + 4 > 63) ? 63 : t0 + 4;
        TILE(0, 2, t0 + 2);
        TILE(1, 0, u1);
        TILE(2, 1, u2);
    }
    TILE(0, 2, 63);                       // tile 63 (dummy stage, buf2 free)
    VMCNT0;                               // drain dummies before LDS teardown

    // epilogue: C/D layout col = lane&15, row = (lane>>4)*4 + reg
    const int orow0 = row0 + wmp * 64;
    const int ocol0 = col0 + wnp * 64;
    #pragma unroll
    for (int fn = 0; fn < 4; ++fn) {
        const int col = ocol0 + fn * 16 + l15;
        const float sw = scale_w[col];
        const float bv = bias[col];
        #pragma unroll
        for (int fm = 0; fm < 4; ++fm) {
            #pragma unroll
            for (int j = 0; j < 4; ++j) {
                const int row = orow0 + fm * 16 + l16 * 4 + j;
                out[(size_t)row * NDIM + col] =
                    (float)acc[fm][fn][j] * scale_x[row] * sw + bv;
            }
        }
    }
#undef STAGE_A
#undef STAGE_B
#undef LDA
#undef LDB
#undef MMA_ALL
#undef TILE
#undef FENCE
#undef BAR
#undef VMCNT3
#undef VMCNT0
#undef PRIO1
#undef PRIO0
}

// ---------------------------------------------------------------------------
extern "C" void kernel_launch(void* const* d_in, const int* in_sizes, int n_in,
                              void* d_out, int out_size, void* d_ws, size_t ws_size,
                              hipStream_t stream)
{
    const float* x        = (const float*)d_in[0];
    const int*   Wq       = (const int*)d_in[1];
    const float* scale    = (const float*)d_in[2];
    const float* zp       = (const float*)d_in[3];
    const float* svd_up   = (const float*)d_in[4];
    const float* svd_down = (const float*)d_in[5];
    const float* bias     = (const float*)d_in[6];
    float* out = (float*)d_out;

    // ws: xq 16MB | wq 16MB | scale_x 16KB | scale_w 16KB | partial 1MB |
    //     upb 1MB | dnt 1MB
    int8_t* xq = (int8_t*)d_ws;
    int8_t* wq = (int8_t*)d_ws + ((size_t)16 << 20);
    float* scale_x = (float*)((char*)d_ws + ((size_t)32 << 20));
    float* scale_w = scale_x + TDIM;
    float* partial_max = scale_w + NDIM;
    unsigned short* upb = (unsigned short*)(partial_max + (size_t)NDIM * NCHUNK);
    unsigned short* dnt = upb + (size_t)NDIM * RANK;

    // d_out doubles as fp32 Wf scratch (64MB) — fully overwritten by the GEMM.
    float* Wf = out;

    quant_x_kernel<<<TDIM, 256, 0, stream>>>(x, xq, scale_x);
    conv_svd_kernel<<<384, 256, 0, stream>>>(svd_up, svd_down, upb, dnt);
    w_pass1_mfma_kernel<<<dim3(NDIM / 64, KDIM / 128), 256, 0, stream>>>(
        Wq, scale, zp, upb, dnt, Wf, partial_max);
    finalize_sw_kernel<<<NDIM / 256, 256, 0, stream>>>(partial_max, scale_w);
    w_quant_kernel<<<(size_t)NDIM * KDIM / (256 * 4), 256, 0, stream>>>(Wf, scale_w, wq);
    gemm_i8_kernel<<<(TDIM / 128) * (NDIM / 256), 512, 0, stream>>>(
        xq, wq, scale_x, scale_w, bias, out);
}

// Round 8
// 133.911 us; speedup vs baseline: 1.3026x; 1.3026x over previous
//
#include <hip/hip_runtime.h>
#include <stdint.h>

#define TDIM 4096   // tokens = 2*2048
#define KDIM 4096   // IN_F
#define NDIM 4096   // OUT_F
#define RANK 128
#define NG   32

typedef __attribute__((ext_vector_type(4))) int   i32x4;
typedef __attribute__((ext_vector_type(4))) float f32x4;
typedef __attribute__((ext_vector_type(8))) short short8;
typedef __attribute__((ext_vector_type(8))) unsigned short u16x8;
typedef __attribute__((ext_vector_type(8))) char c8;

__device__ inline unsigned short f2bf(float f) {   // f32 -> bf16 RNE
    union { float f; unsigned u; } v; v.f = f;
    const unsigned r = v.u + 0x7FFF + ((v.u >> 16) & 1);
    return (unsigned short)(r >> 16);
}
__device__ inline float bf2f(unsigned short h) {
    union { unsigned u; float f; } v; v.u = (unsigned)h << 16;
    return v.f;
}

// ---------------------------------------------------------------------------
// Kernel 1: per-token activation quantization (unchanged).
// ---------------------------------------------------------------------------
__global__ __launch_bounds__(256) void quant_x_kernel(
    const float* __restrict__ x, int8_t* __restrict__ xq,
    float* __restrict__ scale_x)
{
    const int row = blockIdx.x;
    const float4* xr = (const float4*)(x + (size_t)row * KDIM);
    __shared__ float4 buf[1024];
    __shared__ float wred[4];

    float m = 0.f;
    #pragma unroll
    for (int j = 0; j < 4; ++j) {
        const float4 v = xr[threadIdx.x + j * 256];
        buf[threadIdx.x + j * 256] = v;
        m = fmaxf(m, fmaxf(fmaxf(fabsf(v.x), fabsf(v.y)),
                           fmaxf(fabsf(v.z), fabsf(v.w))));
    }
    #pragma unroll
    for (int off = 32; off > 0; off >>= 1)
        m = fmaxf(m, __shfl_xor(m, off, 64));
    if ((threadIdx.x & 63) == 0) wred[threadIdx.x >> 6] = m;
    __syncthreads();
    const float mt = fmaxf(fmaxf(wred[0], wred[1]), fmaxf(wred[2], wred[3]));
    const float sx = mt / 127.0f;
    if (threadIdx.x == 0) scale_x[row] = sx;

    char4* xo = (char4*)(xq + (size_t)row * KDIM);
    #pragma unroll
    for (int j = 0; j < 4; ++j) {
        const float4 v = buf[threadIdx.x + j * 256];
        char4 q;
        q.x = (char)fminf(fmaxf(rintf(v.x / sx), -128.f), 127.f);
        q.y = (char)fminf(fmaxf(rintf(v.y / sx), -128.f), 127.f);
        q.z = (char)fminf(fmaxf(rintf(v.z / sx), -128.f), 127.f);
        q.w = (char)fminf(fmaxf(rintf(v.w / sx), -128.f), 127.f);
        xo[threadIdx.x + j * 256] = q;
    }
}

// ---------------------------------------------------------------------------
// Kernel 1b: convert svd factors to bf16 (unchanged).
// ---------------------------------------------------------------------------
__global__ __launch_bounds__(256) void conv_svd_kernel(
    const float* __restrict__ svd_up, const float* __restrict__ svd_down,
    unsigned short* __restrict__ upb, unsigned short* __restrict__ dnt)
{
    const int b = blockIdx.x;
    if (b < 256) {
        const int t = b * 256 + threadIdx.x;
        const int i  = t >> 4;
        const int k0 = (t & 15) * 8;
        u16x8 v;
        #pragma unroll
        for (int j = 0; j < 8; ++j)
            v[j] = f2bf(svd_down[(size_t)(k0 + j) * KDIM + i]);
        *(u16x8*)(dnt + (size_t)i * RANK + k0) = v;
    } else {
        const int t = (b - 256) * 256 + threadIdx.x;
        const float4* src = (const float4*)svd_up + (size_t)t * 4;
        #pragma unroll
        for (int h = 0; h < 2; ++h) {
            const float4 a = src[h * 2], c = src[h * 2 + 1];
            u16x8 v;
            v[0] = f2bf(a.x); v[1] = f2bf(a.y); v[2] = f2bf(a.z); v[3] = f2bf(a.w);
            v[4] = f2bf(c.x); v[5] = f2bf(c.y); v[6] = f2bf(c.z); v[7] = f2bf(c.w);
            *(u16x8*)(upb + (size_t)t * 16 + h * 8) = v;
        }
    }
}

// ---------------------------------------------------------------------------
// Kernel 2 (R7, FUSED): dequant + SVD corr + per-row max + quantize -> wq,
// scale_w. Replaces w_pass1_mfma + finalize_sw + w_quant; eliminates the
// 64MB fp32 Wf HBM round-trip (128 MB scratch traffic).
// Block = 16 out-rows x 4096 cols, 8 waves; wave w owns cols [w*512,+512)
// in 4 chunks of 128 (= exactly one quant group per chunk).
// Pass 1: corr via mfma_f32_16x16x32_bf16 (A=up rows via l15, K=128 -> 4
// steps; validated layout), wf = (Wq-zp)*s + corr, store bf16 to LDS,
// row-max via integer compare on (bf16&0x7FFF).
// LDS layout wfls[row][col ^ ((row>>2&3)<<4)]: XOR moves the 4 l16 row
// groups to disjoint bank octets (<=2-way, same-dword pairs); pass-2 reads
// of 8-aligned col runs stay contiguous (XOR touches bits 4-5 only).
// Pass 2: each thread quantizes 128 cols of one row from LDS, writes
// coalesced char8. True division (rintf(wf/sw)) as validated.
// ---------------------------------------------------------------------------
__global__ __launch_bounds__(512) void fused_w_kernel(
    const int* __restrict__ Wq, const float* __restrict__ scale,
    const float* __restrict__ zp,
    const unsigned short* __restrict__ upb,   // [4096][128] bf16
    const unsigned short* __restrict__ dnt,   // [4096][128] bf16 (down^T)
    int8_t* __restrict__ wq, float* __restrict__ scale_w)
{
    __shared__ unsigned short wfls[16 * 4096];   // 128 KB
    __shared__ float red[16][8];
    __shared__ float swls[16];

    const int tid  = threadIdx.x;
    const int lane = tid & 63, wid = tid >> 6;   // 8 waves
    const int l15  = lane & 15, l16 = lane >> 4;
    const int o0   = blockIdx.x * 16;

    // A fragments: up rows o0..o0+15 (M = l15), K = 128
    short8 af[4];
    #pragma unroll
    for (int kk = 0; kk < 4; ++kk)
        af[kk] = *(const short8*)(upb + (size_t)(o0 + l15) * RANK + kk * 32 + l16 * 8);

    const int swz = l16 << 4;      // row-group XOR for LDS bank spread
    unsigned umax[4] = {0u, 0u, 0u, 0u};

    for (int c = 0; c < 4; ++c) {
        const int cb = wid * 512 + c * 128;
        const int g  = cb >> 7;                  // one group per chunk

        f32x4 acc[8];
        #pragma unroll
        for (int t = 0; t < 8; ++t) acc[t] = (f32x4){0.f, 0.f, 0.f, 0.f};
        #pragma unroll
        for (int t = 0; t < 8; ++t)
            #pragma unroll
            for (int kk = 0; kk < 4; ++kk) {
                const short8 bfr = *(const short8*)(dnt +
                    (size_t)(cb + t * 16 + l15) * RANK + kk * 32 + l16 * 8);
                acc[t] = __builtin_amdgcn_mfma_f32_16x16x32_bf16(
                             af[kk], bfr, acc[t], 0, 0, 0);
            }

        float s[4], z[4];
        #pragma unroll
        for (int j = 0; j < 4; ++j) {
            const int row = o0 + l16 * 4 + j;
            s[j] = scale[row * NG + g];
            z[j] = zp[row * NG + g];
        }

        #pragma unroll
        for (int t = 0; t < 8; ++t) {
            const int col = cb + t * 16 + l15;
            #pragma unroll
            for (int j = 0; j < 4; ++j) {
                const int r = l16 * 4 + j;
                const float q  = (float)Wq[(size_t)(o0 + r) * KDIM + col];
                const float wf = (q - z[j]) * s[j] + acc[t][j];
                const unsigned short h = f2bf(wf);
                wfls[r * 4096 + (col ^ swz)] = h;
                const unsigned a = h & 0x7FFFu;
                umax[j] = (a > umax[j]) ? a : umax[j];
            }
        }
    }

    // per-row max: reduce over the 16 l15 lanes sharing each row
    #pragma unroll
    for (int j = 0; j < 4; ++j) {
        unsigned v = umax[j];
        v = max(v, (unsigned)__shfl_xor((int)v, 1, 64));
        v = max(v, (unsigned)__shfl_xor((int)v, 2, 64));
        v = max(v, (unsigned)__shfl_xor((int)v, 4, 64));
        v = max(v, (unsigned)__shfl_xor((int)v, 8, 64));
        if (l15 == 0) red[l16 * 4 + j][wid] = bf2f((unsigned short)v);
    }
    __syncthreads();
    if (tid < 16) {
        float m = 0.f;
        #pragma unroll
        for (int w = 0; w < 8; ++w) m = fmaxf(m, red[tid][w]);
        const float sw = m / 127.0f;
        swls[tid] = sw;
        scale_w[o0 + tid] = sw;
    }
    __syncthreads();

    // pass 2: quantize from LDS, coalesced char8 stores
    const int r  = tid >> 5;               // 0..15
    const int ml = tid & 31;
    const float sw = swls[r];
    const int rsw = ((r >> 2) & 3) << 4;
    int8_t* wrow = wq + (size_t)(o0 + r) * KDIM;
    #pragma unroll
    for (int k = 0; k < 16; ++k) {
        const int c0 = k * 256 + ml * 8;    // 8-aligned; XOR keeps contiguity
        const u16x8 h = *(const u16x8*)(wfls + r * 4096 + (c0 ^ rsw));
        c8 qv;
        #pragma unroll
        for (int e = 0; e < 8; ++e) {
            float f = bf2f((unsigned short)h[e]);
            qv[e] = (char)fminf(fmaxf(rintf(f / sw), -128.f), 127.f);
        }
        *(c8*)(wrow + c0) = qv;
    }
}

// ---------------------------------------------------------------------------
// Kernel 4: int8 GEMM — REVERTED to R5 4-deep 256x256 (best measured: 72us,
// FETCH 74MB). R6's 128x256 2-blocks/CU halved arithmetic intensity and
// doubled HBM fetch (138MB) — traffic-bound regression.
// ---------------------------------------------------------------------------
__global__ __launch_bounds__(512, 2) void gemm_i8_kernel(
    const int8_t* __restrict__ Aq,   // [T][K]
    const int8_t* __restrict__ Bq,   // [N][K]
    const float* __restrict__ scale_x, const float* __restrict__ scale_w,
    const float* __restrict__ bias, float* __restrict__ out)
{
    __shared__ __align__(16) int8_t lds[131072];
    // A: buf*16384 + h*8192 (128 rows x 64B), bufs 0..3 in [0,64K)
    // B: 65536 + buf*16384 + h*8192             in [64K,128K)

    const int tid  = threadIdx.x;
    const int lane = tid & 63;
    const int wid  = tid >> 6;
    const int wmp  = wid >> 2;
    const int wnp  = wid & 3;
    const int l15  = lane & 15, l16 = lane >> 4;

    const int swz  = (blockIdx.x & 7) * 32 + (blockIdx.x >> 3);
    const int row0 = (swz >> 4) * 256;
    const int col0 = (swz & 15) * 256;

    const int srow = wid * 16 + (lane >> 2);
    const int scol = ((lane & 3) ^ ((lane >> 3) & 3)) * 16;
    const int8_t* const A0 = Aq + (size_t)(row0 + srow) * KDIM + scol;
    const int8_t* const B0 = Bq + (size_t)(col0 + srow) * KDIM + scol;
    int8_t* const ldsw = lds + wid * 1024;

#define STAGE_A(db, h, kt) \
    __builtin_amdgcn_global_load_lds( \
        (const __attribute__((address_space(1))) void*)(A0 + (size_t)(h) * 128 * KDIM + (kt) * 64), \
        (__attribute__((address_space(3))) void*)(ldsw + (db) * 16384 + (h) * 8192), 16, 0, 0)
#define STAGE_B(db, h, kt) \
    __builtin_amdgcn_global_load_lds( \
        (const __attribute__((address_space(1))) void*)(B0 + (size_t)(h) * 128 * KDIM + (kt) * 64), \
        (__attribute__((address_space(3))) void*)(ldsw + 65536 + (db) * 16384 + (h) * 8192), 16, 0, 0)

    const int rslot = (l16 ^ ((lane >> 1) & 3)) * 16;
    const int aoff = wmp * 8192 + l15 * 64 + rslot;
    const int boff = (wnp >> 1) * 8192 + (wnp & 1) * 4096 + l15 * 64 + rslot;

    i32x4 Ar[4], Br[2][2];
    i32x4 acc[8][4];
    #pragma unroll
    for (int m = 0; m < 8; ++m)
        #pragma unroll
        for (int n = 0; n < 4; ++n) acc[m][n] = (i32x4){0, 0, 0, 0};

#define LDA(db, qm) { const int8_t* p = lds + (db) * 16384 + aoff + (qm) * 4096; \
    Ar[0] = *(const i32x4*)(p);        Ar[1] = *(const i32x4*)(p + 1024); \
    Ar[2] = *(const i32x4*)(p + 2048); Ar[3] = *(const i32x4*)(p + 3072); }
#define LDB(db, qn) { const int8_t* p = lds + 65536 + (db) * 16384 + boff + (qn) * 2048; \
    Br[qn][0] = *(const i32x4*)(p);    Br[qn][1] = *(const i32x4*)(p + 1024); }
#define MMA(qm, qn) { \
    _Pragma("unroll") for (int fm = 0; fm < 4; ++fm) \
    _Pragma("unroll") for (int fn = 0; fn < 2; ++fn) \
        acc[(qm) * 4 + fm][(qn) * 2 + fn] = __builtin_amdgcn_mfma_i32_16x16x64_i8( \
            Ar[fm], Br[qn][fn], acc[(qm) * 4 + fm][(qn) * 2 + fn], 0, 0, 0); }

#define FENCE asm volatile("" ::: "memory")
#define BAR   __builtin_amdgcn_s_barrier()
#define VMCNT8 asm volatile("s_waitcnt vmcnt(8)" ::: "memory")
#define PRIO1 __builtin_amdgcn_s_setprio(1)
#define PRIO0 __builtin_amdgcn_s_setprio(0)

#define TILE(b, sb, u) { \
    LDA(b, 0); LDB(b, 0); LDB(b, 1); \
    FENCE; STAGE_A(sb, 0, u); STAGE_A(sb, 1, u); \
    BAR; PRIO1; MMA(0, 0); MMA(0, 1); PRIO0; BAR; \
    LDA(b, 1); \
    FENCE; STAGE_B(sb, 0, u); STAGE_B(sb, 1, u); VMCNT8; \
    BAR; PRIO1; MMA(1, 0); MMA(1, 1); PRIO0; BAR; }

    STAGE_A(0, 0, 0); STAGE_A(0, 1, 0); STAGE_B(0, 0, 0); STAGE_B(0, 1, 0);
    STAGE_A(1, 0, 1); STAGE_A(1, 1, 1); STAGE_B(1, 0, 1); STAGE_B(1, 1, 1);
    STAGE_A(2, 0, 2); STAGE_A(2, 1, 2); STAGE_B(2, 0, 2); STAGE_B(2, 1, 2);
    VMCNT8;
    BAR;

    for (int j = 0; j < 16; ++j) {
        const int t0 = 4 * j;
        const int u1 = (t0 + 4 > 63) ? 63 : t0 + 4;
        const int u2 = (t0 + 5 > 63) ? 63 : t0 + 5;
        const int u3 = (t0 + 6 > 63) ? 63 : t0 + 6;
        TILE(0, 3, t0 + 3);
        TILE(1, 0, u1);
        TILE(2, 1, u2);
        TILE(3, 2, u3);
    }

    const int orow0 = row0 + wmp * 128;
    const int ocol0 = col0 + wnp * 64;
    #pragma unroll
    for (int fn = 0; fn < 4; ++fn) {
        const int col = ocol0 + fn * 16 + l15;
        const float sw = scale_w[col];
        const float bv = bias[col];
        #pragma unroll
        for (int fm = 0; fm < 8; ++fm) {
            #pragma unroll
            for (int j = 0; j < 4; ++j) {
                const int row = orow0 + fm * 16 + l16 * 4 + j;
                out[(size_t)row * NDIM + col] =
                    (float)acc[fm][fn][j] * scale_x[row] * sw + bv;
            }
        }
    }
#undef STAGE_A
#undef STAGE_B
#undef LDA
#undef LDB
#undef MMA
#undef TILE
#undef FENCE
#undef BAR
#undef VMCNT8
#undef PRIO1
#undef PRIO0
}

// ---------------------------------------------------------------------------
extern "C" void kernel_launch(void* const* d_in, const int* in_sizes, int n_in,
                              void* d_out, int out_size, void* d_ws, size_t ws_size,
                              hipStream_t stream)
{
    const float* x        = (const float*)d_in[0];
    const int*   Wq       = (const int*)d_in[1];
    const float* scale    = (const float*)d_in[2];
    const float* zp       = (const float*)d_in[3];
    const float* svd_up   = (const float*)d_in[4];
    const float* svd_down = (const float*)d_in[5];
    const float* bias     = (const float*)d_in[6];
    float* out = (float*)d_out;

    // ws: xq 16MB | wq 16MB | scale_x 16KB | scale_w 16KB | upb 1MB | dnt 1MB
    int8_t* xq = (int8_t*)d_ws;
    int8_t* wq = (int8_t*)d_ws + ((size_t)16 << 20);
    float* scale_x = (float*)((char*)d_ws + ((size_t)32 << 20));
    float* scale_w = scale_x + TDIM;
    unsigned short* upb = (unsigned short*)(scale_w + NDIM);
    unsigned short* dnt = upb + (size_t)NDIM * RANK;

    quant_x_kernel<<<TDIM, 256, 0, stream>>>(x, xq, scale_x);
    conv_svd_kernel<<<384, 256, 0, stream>>>(svd_up, svd_down, upb, dnt);
    fused_w_kernel<<<NDIM / 16, 512, 0, stream>>>(Wq, scale, zp, upb, dnt,
                                                  wq, scale_w);
    gemm_i8_kernel<<<(TDIM / 256) * (NDIM / 256), 512, 0, stream>>>(
        xq, wq, scale_x, scale_w, bias, out);
}